// Round 11
// baseline (123.514 us; speedup 1.0000x reference)
//
#include <hip/hip_runtime.h>
#include <hip/hip_bf16.h>

#define NN 100000
#define NE 1600000
#define FIN 65
#define HID 128
#define NC 32
#define OUTC 65
#define NBUCK 391                     // ceil(NN / 256); bucket = dst >> 8
#define CHUNKS 400
#define CH 4000                       // edges per chunk; CHUNKS*CH == NE
#define ESTRIDE 5120                  // padded slots per bucket (mean 4096, sd 64)
#define NODE_BLOCKS 1563              // ceil(NN / 64)

typedef __attribute__((ext_vector_type(8))) short s8v;    // 8 bf16 (4 VGPRs)
typedef __attribute__((ext_vector_type(4))) float f4v;    // MFMA accumulator
#define MFMA16(a, b, c) __builtin_amdgcn_mfma_f32_16x16x32_bf16(a, b, c, 0, 0, 0)

__device__ __forceinline__ float lrelu(float v){ return v > 0.f ? v : 0.2f * v; }
// round-to-nearest-even f32 -> bf16 bits (finite inputs)
__device__ __forceinline__ short f2bs(float f){
  unsigned u = __float_as_uint(f);
  u += 0x7fffu + ((u >> 16) & 1u);
  return (short)(u >> 16);
}
__device__ __forceinline__ float bfu_lo(unsigned u){ return __uint_as_float(u << 16); }
__device__ __forceinline__ float bfu_hi(unsigned u){ return __uint_as_float(u & 0xffff0000u); }

// ---------------------------------------------------------------------------
// Kernel 0: one-time frag-order weight transpose + cursor zeroing.
// ---------------------------------------------------------------------------
__global__ __launch_bounds__(256) void k_prep(
    const float* __restrict__ Wmlp, const float* __restrict__ W1,
    const float* __restrict__ W2, short* __restrict__ wbg,
    int* __restrict__ bcursor)
{
  const int i = blockIdx.x * 256 + threadIdx.x;   // 0..8191
  if (blockIdx.x == 0)
    for (int t = threadIdx.x; t < NBUCK; t += 256) bcursor[t] = 0;
  {
    const int j = i & 7, l = (i >> 3) & 63, nt = (i >> 9) & 7, t = i >> 12;
    const int k = t * 32 + ((l >> 4) << 3) + j;
    const int col = (nt << 4) + (l & 15);
    wbg[i] = f2bs(Wmlp[k * HID + col]);
  }
  {
    const int j = i & 7, l = (i >> 3) & 63, nt = (i >> 9) & 3, t = i >> 11;
    const int k = t * 32 + ((l >> 4) << 3) + j;
    const int col = (nt << 4) + (l & 15);
    wbg[8192 + i] = f2bs(col < NC ? W1[k * NC + col] : W2[k * NC + col - NC]);
  }
}

// ---------------------------------------------------------------------------
// Kernel 1 (fused): blocks [0, NODE_BLOCKS) = MFMA front-end (stage-1 weight
// frags hoisted into registers BEFORE the staging barrier for ILP);
// blocks [NODE_BLOCKS, +CHUNKS) = edge bucket-scatter.
// ---------------------------------------------------------------------------
__global__ __launch_bounds__(256) void k_main(
    const float* __restrict__ x, const short* __restrict__ wbg,
    const float* __restrict__ Wmlp, const float* __restrict__ bmlp,
    const float* __restrict__ a1s, const float* __restrict__ a1d,
    const float* __restrict__ a2s, const float* __restrict__ a2d,
    const int* __restrict__ ei,
    unsigned short* __restrict__ hb16,
    float* __restrict__ sd2, float* __restrict__ dd2,
    float* __restrict__ out,
    int* __restrict__ bcursor, int* __restrict__ ebuf)
{
  __shared__ alignas(16) char smem[28416];
  const int tid = threadIdx.x;

  if (blockIdx.x >= NODE_BLOCKS) {
    // ---------------- scatter branch ----------------
    const int cb = blockIdx.x - NODE_BLOCKS;
    int* lh = (int*)smem;            // NBUCK counts / cursors
    int* lbase = lh + NBUCK;         // NBUCK bases
    for (int i = tid; i < NBUCK; i += 256) lh[i] = 0;
    __syncthreads();
    const int4* s4 = (const int4*)ei + cb * (CH / 4);
    const int4* d4 = (const int4*)(ei + NE) + cb * (CH / 4);
    for (int i = tid; i < CH / 4; i += 256) {
      int4 v = d4[i];
      atomicAdd(&lh[v.x >> 8], 1);
      atomicAdd(&lh[v.y >> 8], 1);
      atomicAdd(&lh[v.z >> 8], 1);
      atomicAdd(&lh[v.w >> 8], 1);
    }
    __syncthreads();
    for (int i = tid; i < NBUCK; i += 256) {
      int c = lh[i];
      lbase[i] = c ? (i * ESTRIDE + atomicAdd(&bcursor[i], c)) : 0;
      lh[i] = 0;
    }
    __syncthreads();
    for (int i = tid; i < CH / 4; i += 256) {
      int4 sv = s4[i];
      int4 dv = d4[i];
      int b, r;
      b = dv.x >> 8; r = atomicAdd(&lh[b], 1); ebuf[lbase[b] + r] = (sv.x << 8) | (dv.x & 255);
      b = dv.y >> 8; r = atomicAdd(&lh[b], 1); ebuf[lbase[b] + r] = (sv.y << 8) | (dv.y & 255);
      b = dv.z >> 8; r = atomicAdd(&lh[b], 1); ebuf[lbase[b] + r] = (sv.z << 8) | (dv.z & 255);
      b = dv.w >> 8; r = atomicAdd(&lh[b], 1); ebuf[lbase[b] + r] = (sv.w << 8) | (dv.w & 255);
    }
    return;
  }

  // ---------------- node branch (MFMA front-end) ----------------
  short* xbf = (short*)smem;                   // 64*72 bf16   9216 B
  short* x0b = (short*)(smem + 9216);          // 64*136 bf16 17408 B
  float* xc64 = (float*)(smem + 26624);        // 64
  float* w64 = (float*)(smem + 26880);         // 128
  float* bmv = (float*)(smem + 27392);         // 128
  float* avv = (float*)(smem + 27904);         // 128

  const int base = blockIdx.x * 64;
  const int w = tid >> 6, lane = tid & 63;
  const s8v* wv8 = (const s8v*)wbg;

  // hoist ALL stage-1 weight frags: 16 independent loads in flight while
  // the x rows are being staged (they don't depend on LDS).
  s8v bw[16];
  #pragma unroll
  for (int nt = 0; nt < 16; ++nt) bw[nt] = wv8[nt * 64 + lane];

  if (tid < 128) { w64[tid] = Wmlp[64 * HID + tid]; bmv[tid] = bmlp[tid]; }
  else if (tid < 160) {
    const int q = tid - 128;
    avv[q] = a1s[q]; avv[32 + q] = a1d[q]; avv[64 + q] = a2s[q]; avv[96 + q] = a2d[q];
  }
  for (int i = tid; i < 64 * 65; i += 256) {
    const int r = i / 65, c = i - r * 65;
    const int node = base + r;
    const float v = (node < NN) ? x[(size_t)node * FIN + c] : 0.f;
    if (c == 64) xc64[r] = v; else xbf[r * 72 + c] = f2bs(v);
  }
  __syncthreads();

  const int g = lane >> 4, q = lane & 15;
  const int rowA = w * 16 + q;
  const int rowD0 = w * 16 + g * 4;

  // ---- stage 1: x0 = relu(x@Wmlp + b) ----
  const s8v a0 = *(const s8v*)&xbf[rowA * 72 + g * 8];
  const s8v a1 = *(const s8v*)&xbf[rowA * 72 + 32 + g * 8];

  f4v acc[8];
  #pragma unroll
  for (int nt = 0; nt < 8; ++nt) acc[nt] = (f4v){0.f, 0.f, 0.f, 0.f};
  #pragma unroll
  for (int nt = 0; nt < 8; ++nt) {
    acc[nt] = MFMA16(a0, bw[nt], acc[nt]);
    acc[nt] = MFMA16(a1, bw[8 + nt], acc[nt]);
  }

  // hoist stage-2 weight frags now: loads fly while the stage-1 epilogue
  // (bias/relu/rowmax/x0b stores) runs on the VALU.
  s8v bw2[16];
  #pragma unroll
  for (int t2 = 0; t2 < 16; ++t2) bw2[t2] = wv8[1024 + t2 * 64 + lane];

  float xc[4];
  #pragma unroll
  for (int r = 0; r < 4; ++r) xc[r] = xc64[rowD0 + r];
  float rmax[4] = {0.f, 0.f, 0.f, 0.f};
  #pragma unroll
  for (int nt = 0; nt < 8; ++nt) {
    const int col = nt * 16 + q;
    const float wvv = w64[col], bv = bmv[col];
    #pragma unroll
    for (int r = 0; r < 4; ++r) {
      const float v = fmaxf(fmaf(xc[r], wvv, acc[nt][r]) + bv, 0.f);
      rmax[r] = fmaxf(rmax[r], v);
      x0b[(rowD0 + r) * 136 + col] = f2bs(v);
    }
  }
  #pragma unroll
  for (int off = 1; off < 16; off <<= 1)
    #pragma unroll
    for (int r = 0; r < 4; ++r) rmax[r] = fmaxf(rmax[r], __shfl_xor(rmax[r], off));
  if (q == 0) {
    #pragma unroll
    for (int r = 0; r < 4; ++r) {
      const int node = base + rowD0 + r;
      if (node < NN) out[(size_t)node * OUTC + 64] = rmax[r];
    }
  }

  // ---- stage 2: h = x0 @ [W1|W2] ----
  s8v af[4];
  #pragma unroll
  for (int t2 = 0; t2 < 4; ++t2)
    af[t2] = *(const s8v*)&x0b[rowA * 136 + t2 * 32 + g * 8];
  f4v hacc[4];
  #pragma unroll
  for (int nt = 0; nt < 4; ++nt) hacc[nt] = (f4v){0.f, 0.f, 0.f, 0.f};
  #pragma unroll
  for (int nt = 0; nt < 4; ++nt)
    #pragma unroll
    for (int t2 = 0; t2 < 4; ++t2)
      hacc[nt] = MFMA16(af[t2], bw2[t2 * 4 + nt], hacc[nt]);

  // ---- epilogue ----
  float s1p[4], d1p[4], s2p[4], d2p[4];
  #pragma unroll
  for (int r = 0; r < 4; ++r) {
    s1p[r] = hacc[0][r] * avv[q]        + hacc[1][r] * avv[16 + q];
    d1p[r] = hacc[0][r] * avv[32 + q]   + hacc[1][r] * avv[48 + q];
    s2p[r] = hacc[2][r] * avv[64 + q]   + hacc[3][r] * avv[80 + q];
    d2p[r] = hacc[2][r] * avv[96 + q]   + hacc[3][r] * avv[112 + q];
  }
  #pragma unroll
  for (int off = 1; off < 16; off <<= 1) {
    #pragma unroll
    for (int r = 0; r < 4; ++r) {
      s1p[r] += __shfl_xor(s1p[r], off);
      d1p[r] += __shfl_xor(d1p[r], off);
      s2p[r] += __shfl_xor(s2p[r], off);
      d2p[r] += __shfl_xor(d2p[r], off);
    }
  }
  #pragma unroll
  for (int r = 0; r < 4; ++r) {
    const int node = base + rowD0 + r;
    if (node < NN) {
      #pragma unroll
      for (int nt = 0; nt < 4; ++nt)
        hb16[(size_t)node * 64 + nt * 16 + q] = (unsigned short)f2bs(hacc[nt][r]);
      if (q == 0) {
        *(float2*)&sd2[(size_t)node * 2] = make_float2(s1p[r], s2p[r]);
        *(float2*)&dd2[(size_t)node * 2] = make_float2(d1p[r], d2p[r]);
      }
    }
  }
}

// ---------------------------------------------------------------------------
// k_csr v2: one block per bucket. Per-dst counts -> scan -> packed rpp; then
// per edge: compute softmax weights w1,w2 = exp(lrelu(s+d)) (no max-sub,
// mathematically identical), write compact record int2{src, bf16w1|bf16w2<<16},
// and accumulate per-node denominators via LDS f32 atomics.
// ---------------------------------------------------------------------------
__global__ __launch_bounds__(256) void k_csr(const int* __restrict__ bcursor,
                                             const int* __restrict__ ebuf,
                                             const float* __restrict__ sd2,
                                             const float* __restrict__ dd2,
                                             int* __restrict__ rpp,
                                             int2* __restrict__ erec,
                                             float* __restrict__ den)
{
  __shared__ int lh[256];
  __shared__ float dl2[512];     // dd2 pairs for the block's 256 nodes
  __shared__ float dsum[512];    // den accumulators [dl*2+conv]
  __shared__ int wsum[4];
  const int b = blockIdx.x;
  const int e0 = b * ESTRIDE;
  const int cntb = bcursor[b];
  const int t = threadIdx.x;
  const int node = (b << 8) + t;

  lh[t] = 0;
  dsum[t] = 0.f;
  dsum[256 + t] = 0.f;
  if (node < NN) {
    const float2 dv = *(const float2*)&dd2[(size_t)node * 2];
    dl2[t * 2] = dv.x;
    dl2[t * 2 + 1] = dv.y;
  }
  __syncthreads();

  for (int i = t; i < cntb; i += 256)
    atomicAdd(&lh[ebuf[e0 + i] & 255], 1);
  __syncthreads();

  const int lane = t & 63;
  const int wid = t >> 6;
  int v = lh[t];
  const int orig = v;
  for (int off = 1; off < 64; off <<= 1) {
    int tm = __shfl_up(v, off);
    if (lane >= off) v += tm;
  }
  if (lane == 63) wsum[wid] = v;
  __syncthreads();
  int add = 0;
  for (int ww = 0; ww < wid; ++ww) add += wsum[ww];
  const int ex = v + add - orig;

  if (node < NN) rpp[node] = ((e0 + ex) << 8) | orig;
  __syncthreads();
  lh[t] = ex;
  __syncthreads();

  for (int i = t; i < cntb; i += 256) {
    const int p = ebuf[e0 + i];
    const int dl = p & 255;
    const int s = ((unsigned)p) >> 8;
    const float2 sv = *(const float2*)&sd2[(size_t)s * 2];
    const float w1 = __expf(lrelu(sv.x + dl2[dl * 2]));
    const float w2 = __expf(lrelu(sv.y + dl2[dl * 2 + 1]));
    const unsigned wpk = ((unsigned)(unsigned short)f2bs(w2) << 16)
                       | (unsigned)(unsigned short)f2bs(w1);
    const int r = atomicAdd(&lh[dl], 1);
    erec[e0 + r] = make_int2(s, (int)wpk);
    atomicAdd(&dsum[dl * 2], w1);
    atomicAdd(&dsum[dl * 2 + 1], w2);
  }
  __syncthreads();
  if (node < NN)
    *(float2*)&den[(size_t)node * 2] = make_float2(dsum[t * 2], dsum[t * 2 + 1]);
}

// ---------------------------------------------------------------------------
// k_conv v6: fused dual GAT conv + finalize. 2 nodes/wave, 32 lanes/node:
// sub = hl>>3 (4 edge-slots in flight), cg8 = hl&7 (8 channels), conv = cg8>>2.
// Inner loop: 1 broadcast 8B record load + 1 16B row gather + 8 fma pairs.
// No shuffles, no exp, no Phase A — weights/den precomputed in k_csr.
// ---------------------------------------------------------------------------
__global__ __launch_bounds__(256) void k_conv(
    const int* __restrict__ rpp, const int2* __restrict__ erec,
    const unsigned short* __restrict__ hb16,
    const float* __restrict__ den,
    const float* __restrict__ x,
    const float* __restrict__ b1, const float* __restrict__ b2,
    float* __restrict__ out)
{
  const int wid = threadIdx.x >> 6;
  const int lane = threadIdx.x & 63;
  const int half = lane >> 5;
  const int hl = lane & 31;
  const int sub = hl >> 3;           // edge subslot 0..3
  const int cg8 = hl & 7;            // channels 8*cg8 .. 8*cg8+7
  const int conv = cg8 >> 2;         // 0: ch 0-31 (conv1), 1: ch 32-63 (conv2)

  const int node = blockIdx.x * 8 + wid * 2 + half;

  const int rv = rpp[node];
  const int base = ((unsigned)rv) >> 8;
  const int cnt = rv & 255;
  const float2 dnv = *(const float2*)&den[(size_t)node * 2];
  const float dden = conv ? dnv.y : dnv.x;

  const char* hbp = (const char*)hb16;
  float a[8] = {0.f, 0.f, 0.f, 0.f, 0.f, 0.f, 0.f, 0.f};

  for (int i0 = 0; i0 < cnt; i0 += 4) {
    const int idx = i0 + sub;
    const int2 rec = erec[base + ((idx < cnt) ? idx : (cnt - 1))];
    const unsigned wy = (idx < cnt) ? (unsigned)rec.y : 0u;
    const float wgt = conv ? bfu_hi(wy) : bfu_lo(wy);
    const uint4 pv = *(const uint4*)(hbp + ((size_t)(unsigned)rec.x << 7) + cg8 * 16);
    a[0] = fmaf(wgt, bfu_lo(pv.x), a[0]);
    a[1] = fmaf(wgt, bfu_hi(pv.x), a[1]);
    a[2] = fmaf(wgt, bfu_lo(pv.y), a[2]);
    a[3] = fmaf(wgt, bfu_hi(pv.y), a[3]);
    a[4] = fmaf(wgt, bfu_lo(pv.z), a[4]);
    a[5] = fmaf(wgt, bfu_hi(pv.z), a[5]);
    a[6] = fmaf(wgt, bfu_lo(pv.w), a[6]);
    a[7] = fmaf(wgt, bfu_hi(pv.w), a[7]);
  }

  // fold the 4 sub copies (bits 3,4 of lane stay within the 32-lane half)
  #pragma unroll
  for (int j = 0; j < 8; ++j) {
    a[j] += __shfl_xor(a[j], 8);
    a[j] += __shfl_xor(a[j], 16);
  }

  // ---- fused finalize ----
  const int ch = cg8 * 8;
  const float rden = 1.f / (dden + 1e-16f);
  const float* bp = conv ? (b2 + ch - 32) : (b1 + ch);
  const float4 bva = *(const float4*)bp;
  const float4 bvb = *(const float4*)(bp + 4);
  float v[8];
  v[0] = a[0] * rden + bva.x; v[1] = a[1] * rden + bva.y;
  v[2] = a[2] * rden + bva.z; v[3] = a[3] * rden + bva.w;
  v[4] = a[4] * rden + bvb.x; v[5] = a[5] * rden + bvb.y;
  v[6] = a[6] * rden + bvb.z; v[7] = a[7] * rden + bvb.w;
  if (conv == 0) {
    #pragma unroll
    for (int j = 0; j < 8; ++j) v[j] = fmaxf(v[j], 0.f);
  }
  const float* xr = x + (size_t)node * OUTC;
  float* row = out + (size_t)node * OUTC;
  const float4 xa = *(const float4*)&xr[ch];
  const float4 xb = *(const float4*)&xr[ch + 4];
  v[0] += xa.x; v[1] += xa.y; v[2] += xa.z; v[3] += xa.w;
  v[4] += xb.x; v[5] += xb.y; v[6] += xb.z; v[7] += xb.w;
  const float v64 = row[64] + xr[64];          // x3 (from k_main) + residual

  float mx = v[0];
  #pragma unroll
  for (int j = 1; j < 8; ++j) mx = fmaxf(mx, v[j]);
  #pragma unroll
  for (int off = 1; off < 8; off <<= 1) mx = fmaxf(mx, __shfl_xor(mx, off));
  mx = fmaxf(mx, v64);
  float sm = 0.f;
  #pragma unroll
  for (int j = 0; j < 8; ++j) sm += __expf(v[j] - mx);
  #pragma unroll
  for (int off = 1; off < 8; off <<= 1) sm += __shfl_xor(sm, off);
  sm += __expf(v64 - mx);
  const float ls = __logf(sm) + mx;

  if (sub == 0) {
    *(float4*)&row[ch]     = make_float4(v[0] - ls, v[1] - ls, v[2] - ls, v[3] - ls);
    *(float4*)&row[ch + 4] = make_float4(v[4] - ls, v[5] - ls, v[6] - ls, v[7] - ls);
    if (hl == 0) row[64] = v64 - ls;
  }
}

// ---------------------------------------------------------------------------
extern "C" void kernel_launch(void* const* d_in, const int* in_sizes, int n_in,
                              void* d_out, int out_size, void* d_ws, size_t ws_size,
                              hipStream_t stream)
{
  const float* x    = (const float*)d_in[0];
  const int*   ei   = (const int*)d_in[1];
  const float* Wmlp = (const float*)d_in[2];
  const float* bmlp = (const float*)d_in[3];
  const float* W1   = (const float*)d_in[4];
  const float* a1s  = (const float*)d_in[5];
  const float* a1d  = (const float*)d_in[6];
  const float* b1   = (const float*)d_in[7];
  const float* W2   = (const float*)d_in[8];
  const float* a2s  = (const float*)d_in[9];
  const float* a2d  = (const float*)d_in[10];
  const float* b2   = (const float*)d_in[11];
  float* out = (float*)d_out;

  unsigned short* hb16 = (unsigned short*)d_ws;          // NN*64 bf16 (12.8 MB)
  float* sd2 = (float*)(hb16 + (size_t)NN * 64);         // 2*NN
  float* dd2 = sd2 + (size_t)2 * NN;                     // 2*NN
  float* den = dd2 + (size_t)2 * NN;                     // 2*NN
  int* ebuf   = (int*)(den + (size_t)2 * NN);            // NBUCK*ESTRIDE (8 MB)
  int2* erec  = (int2*)(ebuf + (size_t)NBUCK * ESTRIDE); // NBUCK*ESTRIDE (16 MB)
  int* rpp    = (int*)(erec + (size_t)NBUCK * ESTRIDE);  // NBUCK*256
  int* bcursor= rpp + NBUCK * 256;                       // NBUCK
  short* wbg  = (short*)(bcursor + NBUCK);               // 16384 bf16

  k_prep<<<32, 256, 0, stream>>>(Wmlp, W1, W2, wbg, bcursor);

  k_main<<<NODE_BLOCKS + CHUNKS, 256, 0, stream>>>(
      x, wbg, Wmlp, bmlp, a1s, a1d, a2s, a2d, ei,
      hb16, sd2, dd2, out, bcursor, ebuf);

  k_csr<<<NBUCK, 256, 0, stream>>>(bcursor, ebuf, sd2, dd2, rpp, erec, den);

  k_conv<<<NN / 8, 256, 0, stream>>>(rpp, erec, hb16, den, x, b1, b2, out);
}